// Round 11
// baseline (265.097 us; speedup 1.0000x reference)
//
#include <hip/hip_runtime.h>

namespace {
constexpr int kNH = 8;
constexpr int kK  = 1024;
constexpr int kD  = 128;
constexpr int kB  = 32768;

constexpr int BM  = 128;        // rows per block (mid-tier path)
constexpr int kMarginQ = 4;     // q-bin rescue margin (proven rounds 4-10)
constexpr float kMarginF32 = 0.0625f;

// ws layout (top tier):
// [0] wl_count u32; csq*1024 @4KB (32KB); cbf @64KB (4MB fragment-ordered,
// PRE-SCALED by -2048); part @64KB+4MB (2MB, int2/gid, init 0x7f);
// wl @64KB+6MB.   Mid tier keeps its old offsets (exclusive use).
constexpr size_t kOffCsq  = 4096;
constexpr size_t kOffCbF  = 65536;
constexpr size_t kOffPart = 65536 + 4194304;
constexpr size_t kOffWl9  = 65536 + 4194304 + 2097152;   // top-tier worklist
constexpr size_t kOffWl5  = 65536 + 4194304;             // mid-tier worklist
}

typedef short           bf16x8 __attribute__((ext_vector_type(8)));
typedef float           f32x16 __attribute__((ext_vector_type(16)));

__device__ __forceinline__ unsigned short f2bf_rne(float f) {
    unsigned int x = __float_as_uint(f);
    unsigned int r = (x + 0x7fffu + ((x >> 16) & 1u)) >> 16;
    return (unsigned short)r;
}
__device__ __forceinline__ float bf2f(unsigned short u) {
    return __uint_as_float(((unsigned int)u) << 16);
}
__device__ __forceinline__ int med3_i32(int a, int b, int c) {
    int d;
    asm("v_med3_i32 %0, %1, %2, %3" : "=v"(d) : "v"(a), "v"(b), "v"(c));
    return d;
}

// ---------------------------------------------------------------------------
// Prep: codebook scaled by -2048 (exact), split to bf16 hi/lo in fragment
// order; exact csq*1024 from the ORIGINAL values. Layout per (h,kt,kc,cv)
// 2048B block: hi 1024B | lo 1024B; lane (h32*32+l31) holds 16B =
// code cv*32+l31, k = kc*16 + h32*8 + j.
// ---------------------------------------------------------------------------
__global__ void pq_prep(const float* __restrict__ cb,
                        unsigned short* __restrict__ cbf,
                        float* __restrict__ csq)
{
    int code = blockIdx.x;          // h*1024 + k
    int t = threadIdx.x;            // 0..127 (= d)
    int h = code >> 10, k = code & 1023;
    int kt = k >> 6, cv = (k >> 5) & 1, l31 = k & 31;
    int kc = t >> 4, hh = (t >> 3) & 1, j = t & 7;
    float v = cb[(size_t)code * kD + t];
    float vs = v * -2048.0f;        // exact
    unsigned short hb = f2bf_rne(vs);
    unsigned short lb = f2bf_rne(vs - bf2f(hb));
    size_t base = ((((size_t)h * 16 + kt) * 8 + kc) * 2 + cv) * 2048;
    size_t off  = base + (hh * 32 + l31) * 16 + j * 2;
    *(unsigned short*)((char*)cbf + off)        = hb;
    *(unsigned short*)((char*)cbf + off + 1024) = lb;
    __shared__ double red[128];
    red[t] = (double)v * (double)v;
    __syncthreads();
    for (int s = 64; s > 0; s >>= 1) {
        if (t < s) red[t] += red[t + s];
        __syncthreads();
    }
    if (t == 0) csq[code] = (float)(red[0] * 1024.0);
}

// ---------------------------------------------------------------------------
// Coarse pass v9: 32-codes-per-wave so the panel (64 VGPR) + acc (16) +
// misc (~40) genuinely fits the 128-reg/4-wave budget -> panels stay
// register-resident (no per-tile L2 remat) AND 2 independent 8-wave blocks
// co-reside per CU (tails overlap the other block's MFMA phase).
// Block = (head, K-quarter(256 codes), 1024 rows); 32 tiles of 32 rows.
// Quarters merge via lock-free atomic top-2 insert into part[gid]
// (init 0x7f7f7f7f): old=atomicMin(p1,b1); atomicMin(p2,min(max(old,b1),b2)).
// Correct for concurrent inserts because keys are unique (idx low bits).
// Numerics contract (int keys, q-bin margin 4, fp64 rescue) unchanged.
// ---------------------------------------------------------------------------
__global__ __launch_bounds__(512)
void pq_coarse_mfma9(const float* __restrict__ z,
                     const unsigned short* __restrict__ cbf,
                     const float* __restrict__ csq1024,
                     int2* __restrict__ part)
{
    __shared__ unsigned short zbuf[2][2][32 * kD];   // 32KB [dbuf][hi/lo] swz
    __shared__ int2  P[2][8][32];                    // 4KB per-tile partials
    __shared__ float csel_s[8][2][16];               // 1KB [w][h32][r]

    const int t    = threadIdx.x;
    const int lane = t & 63;
    const int w    = t >> 6;          // wave 0..7
    const int l31  = lane & 31, h32 = lane >> 5;
    const int h    = blockIdx.y;
    const int quar = blockIdx.z;      // K-quarter 0..3
    const int rb0  = blockIdx.x * 1024;

    // ---- csel table: csq*1024 for each (wave, h32, r) acc element ----
    if (t < 256) {
        int ww = t >> 5, hb = (t >> 4) & 1, r = t & 15;
        int cr = (r & 3) + ((r >> 2) << 3) + hb * 4;
        csel_s[ww][hb][r] = csq1024[h * kK + quar * 256 + ww * 32 + cr];
    }

    // ---- per-lane key index addends ----
    int addv[16];
    #pragma unroll
    for (int r = 0; r < 16; ++r)
        addv[r] = quar * 256 + w * 32 + (r & 3) + ((r >> 2) << 3) + h32 * 4;

    // ---- A panel: wave's 32 codes, hi/lo, 64 VGPR (register-resident) ----
    const int cb32 = quar * 8 + w;            // 32-code block 0..31
    bf16x8 Ah[8], Al[8];
    {
        const char* base = (const char*)cbf
            + ((((size_t)h * 16 + (cb32 >> 1)) * 8) * 2 + (cb32 & 1)) * 2048
            + lane * 16;
        #pragma unroll
        for (int kc = 0; kc < 8; ++kc) {
            const char* p = base + (size_t)(kc * 2) * 2048;
            Ah[kc] = *(const bf16x8*)p;
            Al[kc] = *(const bf16x8*)(p + 1024);
        }
    }

    float4 zA, zB;   // pending z loads (T14 issue-early / commit-late)
    auto issueZ = [&](int tile) {
        const float* zp = z + (size_t)(rb0 + tile * 32 + (t >> 4)) * (kNH * kD)
                            + h * kD + (t & 15) * 8;
        zA = *(const float4*)zp;
        zB = *(const float4*)(zp + 4);
    };
    // biased round-half-up bf16 split via v_perm (r7-proven numerics)
    auto commitZ = [&](int buf) {
        unsigned u0 = __float_as_uint(zA.x) + 0x8000u;
        unsigned u1 = __float_as_uint(zA.y) + 0x8000u;
        unsigned u2 = __float_as_uint(zA.z) + 0x8000u;
        unsigned u3 = __float_as_uint(zA.w) + 0x8000u;
        unsigned u4 = __float_as_uint(zB.x) + 0x8000u;
        unsigned u5 = __float_as_uint(zB.y) + 0x8000u;
        unsigned u6 = __float_as_uint(zB.z) + 0x8000u;
        unsigned u7 = __float_as_uint(zB.w) + 0x8000u;
        unsigned h01 = __builtin_amdgcn_perm(u1, u0, 0x07060302u);
        unsigned h23 = __builtin_amdgcn_perm(u3, u2, 0x07060302u);
        unsigned h45 = __builtin_amdgcn_perm(u5, u4, 0x07060302u);
        unsigned h67 = __builtin_amdgcn_perm(u7, u6, 0x07060302u);
        float r0 = zA.x - __uint_as_float(u0 & 0xffff0000u);
        float r1 = zA.y - __uint_as_float(u1 & 0xffff0000u);
        float r2 = zA.z - __uint_as_float(u2 & 0xffff0000u);
        float r3 = zA.w - __uint_as_float(u3 & 0xffff0000u);
        float r4 = zB.x - __uint_as_float(u4 & 0xffff0000u);
        float r5 = zB.y - __uint_as_float(u5 & 0xffff0000u);
        float r6 = zB.z - __uint_as_float(u6 & 0xffff0000u);
        float r7 = zB.w - __uint_as_float(u7 & 0xffff0000u);
        unsigned l01 = __builtin_amdgcn_perm(__float_as_uint(r1) + 0x8000u,
                                             __float_as_uint(r0) + 0x8000u, 0x07060302u);
        unsigned l23 = __builtin_amdgcn_perm(__float_as_uint(r3) + 0x8000u,
                                             __float_as_uint(r2) + 0x8000u, 0x07060302u);
        unsigned l45 = __builtin_amdgcn_perm(__float_as_uint(r5) + 0x8000u,
                                             __float_as_uint(r4) + 0x8000u, 0x07060302u);
        unsigned l67 = __builtin_amdgcn_perm(__float_as_uint(r7) + 0x8000u,
                                             __float_as_uint(r6) + 0x8000u, 0x07060302u);
        int rr = t >> 4, seg = t & 15;
        int off = rr * 256 + ((seg * 16) ^ ((rr & 15) << 4));
        uint4 hv = {h01, h23, h45, h67};
        uint4 lv = {l01, l23, l45, l67};
        *(uint4*)((char*)&zbuf[buf][0][0] + off) = hv;
        *(uint4*)((char*)&zbuf[buf][1][0] + off) = lv;
    };
    auto mergeP = [&](int pb, int tile) {   // threads 0..31 only
        int2 m = P[pb][0][t];
        int m1 = m.x, m2 = m.y;
        #pragma unroll
        for (int ww = 1; ww < 8; ++ww) {
            int2 p = P[pb][ww][t];
            int mx = max(m1, p.x);
            m1 = min(m1, p.x);
            m2 = min(min(m2, p.y), mx);
        }
        // lock-free top-2 insert across the 4 quarter-blocks
        int gid = (rb0 + tile * 32 + t) * kNH + h;
        int old1 = atomicMin(&part[gid].x, m1);
        atomicMin(&part[gid].y, min(max(old1, m1), m2));
    };

    issueZ(0);
    commitZ(0);
    __syncthreads();

    int cur = 0;
    for (int tile = 0; tile < 32; ++tile) {
        if (tile + 1 < 32) issueZ(tile + 1);
        if (tile > 0 && t < 32) mergeP(cur ^ 1, tile - 1);

        // ---- acc C-init = csq*1024 (LDS broadcast) ----
        f32x16 acc;
        __builtin_memcpy(&acc, &csel_s[w][h32][0], 64);

        const char* zh0 = (const char*)&zbuf[cur][0][0];
        const char* zl0 = (const char*)&zbuf[cur][1][0];
        const int boff = l31 * 256;
        const int swz  = (l31 & 15) << 4;
        __builtin_amdgcn_s_setprio(1);
        #pragma unroll
        for (int kc = 0; kc < 8; ++kc) {
            int col = (kc * 32 + h32 * 16) ^ swz;
            bf16x8 Bh = *(const bf16x8*)(zh0 + boff + col);
            bf16x8 Bl = *(const bf16x8*)(zl0 + boff + col);
            acc = __builtin_amdgcn_mfma_f32_32x32x16_bf16(Ah[kc], Bh, acc, 0, 0, 0);
            acc = __builtin_amdgcn_mfma_f32_32x32x16_bf16(Al[kc], Bh, acc, 0, 0, 0);
            acc = __builtin_amdgcn_mfma_f32_32x32x16_bf16(Ah[kc], Bl, acc, 0, 0, 0);
        }
        __builtin_amdgcn_s_setprio(0);
        // ---- per-lane top-2: acc IS the scaled score; 4 VALU per key ----
        int b1 = 0x7fffffff, b2 = 0x7fffffff;
        #pragma unroll
        for (int r = 0; r < 16; ++r) {
            int key = (((int)acc[r]) << 10) + addv[r];
            b2 = med3_i32(key, b1, b2);
            b1 = min(b1, key);
        }
        // fold the two half-wave code sets (same z-row in lane l and l+32)
        int o1 = __shfl_xor(b1, 32), o2 = __shfl_xor(b2, 32);
        int mx2 = max(b1, o1);
        int v1 = min(b1, o1);
        int v2 = min(min(b2, o2), mx2);
        if (h32 == 0) P[cur][w][l31] = make_int2(v1, v2);

        if (tile + 1 < 32) commitZ(cur ^ 1);
        __syncthreads();
        cur ^= 1;
    }
    if (t < 32) mergeP(cur ^ 1, 31);
}

// ---------------------------------------------------------------------------
// Final merge: read part[gid] (already globally merged), idx, worklist flag,
// zq gather.
// ---------------------------------------------------------------------------
__global__ __launch_bounds__(256)
void pq_merge(const int2* __restrict__ part, const float* __restrict__ cb,
              float* __restrict__ out_zq, float* __restrict__ out_idx,
              unsigned int* wl_count, unsigned int* wl, unsigned int wl_cap)
{
    __shared__ int idx_s[128];
    const int t = threadIdx.x;
    const int g0 = blockIdx.x * 128;
    if (t < 128) {
        int gid = g0 + t;
        int2 p = part[gid];
        int idx = p.x & 1023;
        idx_s[t] = idx;
        out_idx[gid] = (float)idx;
        if (wl_cap > 0u && ((p.y >> 10) - (p.x >> 10)) <= kMarginQ) {
            unsigned int pos = atomicAdd(wl_count, 1u);
            if (pos < wl_cap) wl[pos] = (unsigned int)gid;
        }
    }
    __syncthreads();
    #pragma unroll
    for (int it = 0; it < 16; ++it) {
        int c = it * 256 + t;          // 0..4095 float4 chunks
        int row = c >> 5, c4 = c & 31;
        int gid = g0 + row;
        int b = gid >> 3, hh = gid & 7;
        *(float4*)(out_zq + (size_t)b * (kNH * kD) + hh * kD + c4 * 4) =
            *(const float4*)(cb + ((size_t)hh * kK + idx_s[row]) * kD + c4 * 4);
    }
}

// ---------------------------------------------------------------------------
// Mid-tier fallback (pre-scaled cbf: key uses acc + cs).
// ---------------------------------------------------------------------------
__global__ __launch_bounds__(256, 2)
void pq_coarse_mfma3(const float* __restrict__ z, const float* __restrict__ cb,
                     const unsigned short* __restrict__ cbf,
                     const float* __restrict__ csq1024,
                     float* __restrict__ out_zq, float* __restrict__ out_idx,
                     unsigned int* wl_count, unsigned int* wl, unsigned int wl_cap)
{
    __shared__ float csq_s[kK];
    __shared__ int   idx_s[BM];

    const int t    = threadIdx.x;
    const int h    = blockIdx.y;
    const int b0   = blockIdx.x * BM;
    const int lane = t & 63;
    const int w    = t >> 6;
    const int l31  = lane & 31, h32 = lane >> 5;

    *(float4*)&csq_s[t * 4] = *(const float4*)(csq1024 + h * kK + t * 4);

    bf16x8 Ah[8], Al[8];
    {
        const float* zr = z + (size_t)(b0 + w * 32 + l31) * (kNH * kD) + h * kD + h32 * 8;
        #pragma unroll
        for (int kc = 0; kc < 8; ++kc) {
            float4 a = *(const float4*)(zr + kc * 16);
            float4 b = *(const float4*)(zr + kc * 16 + 4);
            float f[8] = {a.x, a.y, a.z, a.w, b.x, b.y, b.z, b.w};
            bf16x8 hv, lv;
            #pragma unroll
            for (int j = 0; j < 8; ++j) {
                unsigned short hb = f2bf_rne(f[j]);
                hv[j] = (short)hb;
                lv[j] = (short)f2bf_rne(f[j] - bf2f(hb));
            }
            Ah[kc] = hv;
            Al[kc] = lv;
        }
    }
    __syncthreads();

    int b1[16], b2[16];
    #pragma unroll
    for (int r = 0; r < 16; ++r) { b1[r] = 0x7fffffff; b2[r] = 0x7fffffff; }

    const char* bbase = (const char*)cbf + (size_t)h * 524288 + lane * 16;
#define LDSLOT(kt_, kc_, s_)                                                  \
    {                                                                         \
        const char* p_ = bbase + (size_t)(((kt_) * 8 + (kc_)) * 2) * 2048;    \
        Bh0[s_] = *(const bf16x8*)(p_);                                       \
        Bl0[s_] = *(const bf16x8*)(p_ + 1024);                                \
        Bh1[s_] = *(const bf16x8*)(p_ + 2048);                                \
        Bl1[s_] = *(const bf16x8*)(p_ + 3072);                                \
    }

    bf16x8 Bh0[4], Bl0[4], Bh1[4], Bl1[4];
    LDSLOT(0, 0, 0);
    LDSLOT(0, 1, 1);

    for (int kt = 0; kt < 16; ++kt) {
        f32x16 acc0 = (f32x16)0.0f, acc1 = (f32x16)0.0f;
        const int ktn = (kt + 1 < 16) ? kt + 1 : kt;
        #pragma unroll
        for (int kc = 0; kc < 8; ++kc) {
            const int s  = kc & 3;
            const int s2 = (kc + 2) & 3;
            if (kc < 6) { LDSLOT(kt, kc + 2, s2); } else { LDSLOT(ktn, kc - 6, s2); }
            __builtin_amdgcn_s_setprio(1);
            acc0 = __builtin_amdgcn_mfma_f32_32x32x16_bf16(Ah[kc], Bh0[s], acc0, 0, 0, 0);
            acc1 = __builtin_amdgcn_mfma_f32_32x32x16_bf16(Ah[kc], Bh1[s], acc1, 0, 0, 0);
            acc0 = __builtin_amdgcn_mfma_f32_32x32x16_bf16(Al[kc], Bh0[s], acc0, 0, 0, 0);
            acc1 = __builtin_amdgcn_mfma_f32_32x32x16_bf16(Al[kc], Bh1[s], acc1, 0, 0, 0);
            acc0 = __builtin_amdgcn_mfma_f32_32x32x16_bf16(Ah[kc], Bl0[s], acc0, 0, 0, 0);
            acc1 = __builtin_amdgcn_mfma_f32_32x32x16_bf16(Ah[kc], Bl1[s], acc1, 0, 0, 0);
            __builtin_amdgcn_s_setprio(0);
        }
        const float cs0 = csq_s[kt * 64 + l31];
        const float cs1 = csq_s[kt * 64 + 32 + l31];
        const int   kg0 = kt * 64 + l31, kg1 = kg0 + 32;
        #pragma unroll
        for (int r = 0; r < 16; ++r) {
            {
                float kf = acc0[r] + cs0;   // cbf pre-scaled by -2048
                int key = ((int)kf << 10) + kg0;
                int mx = max(b1[r], key); b1[r] = min(b1[r], key); b2[r] = min(b2[r], mx);
            }
            {
                float kf = acc1[r] + cs1;
                int key = ((int)kf << 10) + kg1;
                int mx = max(b1[r], key); b1[r] = min(b1[r], key); b2[r] = min(b2[r], mx);
            }
        }
    }
#undef LDSLOT

    #pragma unroll
    for (int r = 0; r < 16; ++r) {
        int v1 = b1[r], v2 = b2[r];
        #pragma unroll
        for (int m = 1; m < 32; m <<= 1) {
            int o1 = __shfl_xor(v1, m);
            int o2 = __shfl_xor(v2, m);
            int mx = max(v1, o1);
            v1 = min(v1, o1);
            v2 = min(min(v2, o2), mx);
        }
        if (l31 == 0) {
            int row = w * 32 + (r & 3) + ((r >> 2) << 3) + h32 * 4;
            int idx = v1 & 1023;
            idx_s[row] = idx;
            int gid = (b0 + row) * kNH + h;
            out_idx[gid] = (float)idx;
            if (wl_cap > 0u && ((v2 >> 10) - (v1 >> 10)) <= kMarginQ) {
                unsigned int pos = atomicAdd(wl_count, 1u);
                if (pos < wl_cap) wl[pos] = (unsigned int)gid;
            }
        }
    }
    __syncthreads();
    {
        const float* cbh_row = cb + (size_t)h * kK * kD;
        #pragma unroll
        for (int it = 0; it < 16; ++it) {
            int c = it * 256 + t;
            int row = c >> 5, col4 = c & 31;
            *(float4*)(out_zq + (size_t)(b0 + row) * (kNH * kD) + h * kD + col4 * 4) =
                *(const float4*)(cbh_row + (size_t)idx_s[row] * kD + col4 * 4);
        }
    }
}

// ---------------------------------------------------------------------------
// Fallback fp32 coarse pass (round-1, proven) — used only if ws tiny.
// ---------------------------------------------------------------------------
__global__ __launch_bounds__(256, 2)
void pq_coarse_f32(const float* __restrict__ z, const float* __restrict__ cb,
                   float* __restrict__ out_zq, float* __restrict__ out_idx,
                   unsigned int* wl_count, unsigned int* wl, unsigned int wl_cap)
{
    constexpr int KT = 64, PAD = 68, BMF = 64;
    __shared__ float zT[kD][PAD];
    __shared__ float cT[kD][PAD];
    __shared__ float csq_s[KT];
    __shared__ int   bidx_s[BMF];

    const int t  = threadIdx.x;
    const int h  = blockIdx.y;
    const int b0 = blockIdx.x * BMF;
    const int tx = t & 15, ty = t >> 4;
    const int r8 = t & 7,  d4 = t >> 3;

    {
        const float* zp = z + (size_t)(b0 + r8) * (kNH * kD) + h * kD + 4 * d4;
        #pragma unroll
        for (int it = 0; it < BMF / 8; ++it) {
            float4 v = *(const float4*)(zp + (size_t)(8 * it) * (kNH * kD));
            int r = r8 + 8 * it;
            zT[4 * d4 + 0][r] = v.x; zT[4 * d4 + 1][r] = v.y;
            zT[4 * d4 + 2][r] = v.z; zT[4 * d4 + 3][r] = v.w;
        }
    }
    float best1[4], best2[4]; int ibest[4];
    #pragma unroll
    for (int i = 0; i < 4; ++i) { best1[i] = 3.4e38f; best2[i] = 3.4e38f; ibest[i] = 0; }

    for (int kt = 0; kt < kK / KT; ++kt) {
        __syncthreads();
        {
            const float* cp = cb + ((size_t)h * kK + kt * KT + r8) * kD + 4 * d4;
            #pragma unroll
            for (int it = 0; it < KT / 8; ++it) {
                float4 v = *(const float4*)(cp + (size_t)(8 * it) * kD);
                int r = r8 + 8 * it;
                cT[4 * d4 + 0][r] = v.x; cT[4 * d4 + 1][r] = v.y;
                cT[4 * d4 + 2][r] = v.z; cT[4 * d4 + 3][r] = v.w;
            }
        }
        if (t < KT) csq_s[t] = 0.0f;
        __syncthreads();
        {
            int kk = t & 63, part = t >> 6;
            float s = 0.f;
            #pragma unroll
            for (int i = 0; i < 32; ++i) { float v = cT[32 * part + i][kk]; s = fmaf(v, v, s); }
            atomicAdd(&csq_s[kk], s);
        }
        __syncthreads();
        float accA[4][4] = {{0}}, accB[4][4] = {{0}};
        #pragma unroll 2
        for (int d = 0; d < kD; d += 2) {
            float4 za = *(const float4*)&zT[d][4 * ty];
            float4 ca = *(const float4*)&cT[d][4 * tx];
            float4 zb = *(const float4*)&zT[d + 1][4 * ty];
            float4 cv = *(const float4*)&cT[d + 1][4 * tx];
            float zav[4] = {za.x, za.y, za.z, za.w}, cav[4] = {ca.x, ca.y, ca.z, ca.w};
            float zbv[4] = {zb.x, zb.y, zb.z, zb.w}, cbv[4] = {cv.x, cv.y, cv.z, cv.w};
            #pragma unroll
            for (int i = 0; i < 4; ++i)
                #pragma unroll
                for (int j = 0; j < 4; ++j) {
                    accA[i][j] = fmaf(zav[i], cav[j], accA[i][j]);
                    accB[i][j] = fmaf(zbv[i], cbv[j], accB[i][j]);
                }
        }
        #pragma unroll
        for (int j = 0; j < 4; ++j) {
            int kk = 4 * tx + j;
            float cs = csq_s[kk];
            int kg = kt * KT + kk;
            #pragma unroll
            for (int i = 0; i < 4; ++i) {
                float s = fmaf(-2.0f, accA[i][j] + accB[i][j], cs);
                if (s < best1[i]) { best2[i] = best1[i]; best1[i] = s; ibest[i] = kg; }
                else if (s < best2[i]) { best2[i] = s; }
            }
        }
    }
    __syncthreads();
    float* redv1 = &zT[0][0];
    float* redv2 = redv1 + BMF * 16;
    int*   redi  = (int*)(redv2 + BMF * 16);
    #pragma unroll
    for (int i = 0; i < 4; ++i) {
        int r = 4 * ty + i;
        redv1[r * 16 + tx] = best1[i]; redv2[r * 16 + tx] = best2[i]; redi[r * 16 + tx] = ibest[i];
    }
    __syncthreads();
    if (t < BMF) {
        int r = t;
        float vb1_ = redv1[r * 16], vb2_ = redv2[r * 16];
        int i1 = redi[r * 16];
        #pragma unroll
        for (int x = 1; x < 16; ++x) {
            float nb1 = redv1[r * 16 + x], nb2 = redv2[r * 16 + x];
            int ni1 = redi[r * 16 + x];
            if (nb1 < vb1_ || (nb1 == vb1_ && ni1 < i1)) { vb2_ = fminf(vb1_, nb2); vb1_ = nb1; i1 = ni1; }
            else vb2_ = fminf(vb2_, nb1);
        }
        bidx_s[r] = i1;
        int gid = (b0 + r) * kNH + h;
        out_idx[gid] = (float)i1;
        if (wl_cap > 0u && (vb2_ - vb1_) <= kMarginF32) {
            unsigned int pos = atomicAdd(wl_count, 1u);
            if (pos < wl_cap) wl[pos] = (unsigned int)gid;
        }
    }
    __syncthreads();
    {
        int r = t >> 2, q = t & 3;
        const float* src = cb + ((size_t)h * kK + bidx_s[r]) * kD;
        float* dst = out_zq + (size_t)(b0 + r) * (kNH * kD) + h * kD;
        #pragma unroll
        for (int m = 0; m < 8; ++m) {
            int jj = 4 * m + q;
            *(float4*)(dst + 4 * jj) = *(const float4*)(src + 4 * jj);
        }
    }
}

// ---------------------------------------------------------------------------
// Exact fp64 rescore for flagged pairs.
// ---------------------------------------------------------------------------
__global__ __launch_bounds__(256)
void pq_exact(const float* __restrict__ z, const float* __restrict__ cb,
              float* __restrict__ out_zq, float* __restrict__ out_idx,
              const unsigned int* wl_count, const unsigned int* wl,
              unsigned int wl_cap)
{
    if (wl_cap == 0u) return;
    __shared__ float  zs[kD];
    __shared__ double rv[256];
    __shared__ int    ri[256];
    unsigned int n = *wl_count;
    if (n > wl_cap) n = wl_cap;
    const int t = threadIdx.x;
    for (unsigned int e = blockIdx.x; e < n; e += gridDim.x) {
        unsigned int id = wl[e];
        int b = (int)(id / kNH), h = (int)(id % kNH);
        if (t < kD) zs[t] = z[(size_t)b * (kNH * kD) + h * kD + t];
        __syncthreads();
        double bv = 1e300; int bi = 0;
        #pragma unroll
        for (int kk = 0; kk < 4; ++kk) {
            int k = t * 4 + kk;
            const float* c = cb + ((size_t)h * kK + k) * kD;
            double s = 0.0;
            for (int d = 0; d < kD; ++d) {
                double diff = (double)zs[d] - (double)c[d];
                s = fma(diff, diff, s);
            }
            if (s < bv) { bv = s; bi = k; }
        }
        rv[t] = bv; ri[t] = bi;
        __syncthreads();
        for (int s2 = 128; s2 > 0; s2 >>= 1) {
            if (t < s2) {
                if (rv[t + s2] < rv[t] || (rv[t + s2] == rv[t] && ri[t + s2] < ri[t])) {
                    rv[t] = rv[t + s2]; ri[t] = ri[t + s2];
                }
            }
            __syncthreads();
        }
        int kbest = ri[0];
        if (t == 0) out_idx[id] = (float)kbest;
        if (t < kD)
            out_zq[(size_t)b * (kNH * kD) + h * kD + t] =
                cb[((size_t)h * kK + kbest) * kD + t];
        __syncthreads();
    }
}

extern "C" void kernel_launch(void* const* d_in, const int* in_sizes, int n_in,
                              void* d_out, int out_size, void* d_ws, size_t ws_size,
                              hipStream_t stream)
{
    const float* z  = (const float*)d_in[0];
    const float* cb = (const float*)d_in[1];
    float* out_zq  = (float*)d_out;
    float* out_idx = out_zq + (size_t)kB * kNH * kD;
    char* ws = (char*)d_ws;

    if (ws_size >= kOffWl9 + 65536) {
        // ---- top tier: 32-codes/wave, register-resident panels,
        //      2 blocks/CU, atomic quarter-merge ----
        unsigned int* wl_count = (unsigned int*)ws;
        unsigned int* wl = (unsigned int*)(ws + kOffWl9);
        size_t c = (ws_size - kOffWl9) / 4;
        unsigned int cap = (unsigned int)(c > 262144 ? 262144 : c);
        float* csq = (float*)(ws + kOffCsq);
        unsigned short* cbf = (unsigned short*)(ws + kOffCbF);
        int2* part = (int2*)(ws + kOffPart);

        hipMemsetAsync(d_ws, 0, 4, stream);
        hipMemsetAsync(part, 0x7f, (size_t)kB * kNH * 8, stream);  // INF keys
        pq_prep<<<kNH * kK, kD, 0, stream>>>(cb, cbf, csq);
        dim3 grid(32, kNH, 4);
        pq_coarse_mfma9<<<grid, 512, 0, stream>>>(z, cbf, csq, part);
        pq_merge<<<kB * kNH / 128, 256, 0, stream>>>(part, cb, out_zq, out_idx,
                                                     wl_count, wl, cap);
        pq_exact<<<256, 256, 0, stream>>>(z, cb, out_zq, out_idx, wl_count, wl, cap);
    } else if (ws_size >= kOffWl5 + 4096) {
        // ---- mid-tier ----
        unsigned int* wl_count = (unsigned int*)ws;
        unsigned int* wl = (unsigned int*)(ws + kOffWl5);
        size_t c = (ws_size - kOffWl5) / 4;
        unsigned int cap = (unsigned int)(c > 262144 ? 262144 : c);
        float* csq = (float*)(ws + kOffCsq);
        unsigned short* cbf = (unsigned short*)(ws + kOffCbF);

        hipMemsetAsync(d_ws, 0, 4, stream);
        pq_prep<<<kNH * kK, kD, 0, stream>>>(cb, cbf, csq);
        dim3 grid(kB / BM, kNH);
        pq_coarse_mfma3<<<grid, 256, 0, stream>>>(z, cb, cbf, csq,
                                                  out_zq, out_idx, wl_count, wl, cap);
        pq_exact<<<256, 256, 0, stream>>>(z, cb, out_zq, out_idx, wl_count, wl, cap);
    } else {
        unsigned int* wl_count = (unsigned int*)ws;
        unsigned int* wl = wl_count + 1;
        unsigned int cap = 0;
        if (ws_size >= 64) {
            size_t c = ws_size / 4 - 1;
            cap = (unsigned int)(c > 262144 ? 262144 : c);
            hipMemsetAsync(d_ws, 0, 4, stream);
        }
        dim3 grid(kB / 64, kNH);
        pq_coarse_f32<<<grid, 256, 0, stream>>>(z, cb, out_zq, out_idx, wl_count, wl, cap);
        pq_exact<<<256, 256, 0, stream>>>(z, cb, out_zq, out_idx, wl_count, wl, cap);
    }
}

// Round 12
// 226.438 us; speedup vs baseline: 1.1707x; 1.1707x over previous
//
#include <hip/hip_runtime.h>

namespace {
constexpr int kNH = 8;
constexpr int kK  = 1024;
constexpr int kD  = 128;
constexpr int kB  = 32768;

constexpr int BM  = 128;        // rows per block (mid-tier path)
constexpr int kMarginQ = 4;     // q-bin rescue margin (proven rounds 4-10)
constexpr float kMarginF32 = 0.0625f;

// ws layout:
// [0] wl_count u32; csq*1024 @4KB (32KB); cbf @64KB (4MB fragment-ordered,
// PRE-SCALED by -2048); partials @64KB+4MB (4MB); wl @64KB+8MB.
constexpr size_t kOffCsq  = 4096;
constexpr size_t kOffCbF  = 65536;
constexpr size_t kOffPart = 65536 + 4194304;
constexpr size_t kOffWl6  = 65536 + 8388608;          // top-tier worklist
constexpr size_t kOffWl5  = 65536 + 4194304;          // mid-tier worklist
}

typedef short           bf16x8 __attribute__((ext_vector_type(8)));
typedef unsigned short  us16x8 __attribute__((ext_vector_type(8)));
typedef float           f32x16 __attribute__((ext_vector_type(16)));

__device__ __forceinline__ unsigned short f2bf_rne(float f) {
    unsigned int x = __float_as_uint(f);
    unsigned int r = (x + 0x7fffu + ((x >> 16) & 1u)) >> 16;
    return (unsigned short)r;
}
__device__ __forceinline__ float bf2f(unsigned short u) {
    return __uint_as_float(((unsigned int)u) << 16);
}
__device__ __forceinline__ int med3_i32(int a, int b, int c) {
    int d;
    asm("v_med3_i32 %0, %1, %2, %3" : "=v"(d) : "v"(a), "v"(b), "v"(c));
    return d;
}

// ---------------------------------------------------------------------------
// Prep: codebook scaled by -2048 (exact: sign+exponent), split to bf16 hi/lo
// in fragment order; exact csq*1024 from the ORIGINAL values.
// Per (h,kt,kc,cv) 2048B block: hi 1024B | lo 1024B; lane (h32*32+l31) holds
// 16B = code cv*32+l31, k = kc*16 + h32*8 + j.
// With this scaling, MFMA(acc_init=csq*1024) accumulates the int-key score
// directly: acc = csq*1024 - 2048*dot.
// ---------------------------------------------------------------------------
__global__ void pq_prep(const float* __restrict__ cb,
                        unsigned short* __restrict__ cbf,
                        float* __restrict__ csq)
{
    int code = blockIdx.x;          // h*1024 + k
    int t = threadIdx.x;            // 0..127 (= d)
    int h = code >> 10, k = code & 1023;
    int kt = k >> 6, cv = (k >> 5) & 1, l31 = k & 31;
    int kc = t >> 4, hh = (t >> 3) & 1, j = t & 7;
    float v = cb[(size_t)code * kD + t];
    float vs = v * -2048.0f;        // exact
    unsigned short hb = f2bf_rne(vs);
    unsigned short lb = f2bf_rne(vs - bf2f(hb));
    size_t base = ((((size_t)h * 16 + kt) * 8 + kc) * 2 + cv) * 2048;
    size_t off  = base + (hh * 32 + l31) * 16 + j * 2;
    *(unsigned short*)((char*)cbf + off)        = hb;
    *(unsigned short*)((char*)cbf + off + 1024) = lb;
    __shared__ double red[128];
    red[t] = (double)v * (double)v;
    __syncthreads();
    for (int s = 64; s > 0; s >>= 1) {
        if (t < s) red[t] += red[t + s];
        __syncthreads();
    }
    if (t == 0) csq[code] = (float)(red[0] * 1024.0);
}

// ---------------------------------------------------------------------------
// Coarse pass (r9-proven structure) + two zero-numerics-risk schedule edits:
//  (a) commitZ moved BEFORE the key loop: the ds_write drain overlaps the
//      pure-VALU key loop instead of stalling at the barrier. Safe: writes go
//      to buf[cur^1], which no wave reads until after the barrier, and the
//      key loop doesn't touch zbuf.
//  (b) setprio hoisted to wrap the whole MFMA phase (2 toggles/tile vs 16).
// Numerics contract (int keys, q-bin margin 4, fp64 rescue) unchanged.
// ---------------------------------------------------------------------------
__global__ __launch_bounds__(512)
void pq_coarse_mfma7(const float* __restrict__ z,
                     const unsigned short* __restrict__ cbf,
                     const float* __restrict__ csq1024,
                     int2* __restrict__ part)
{
    __shared__ unsigned short zbuf[2][2][32 * kD];   // 32KB [dbuf][hi/lo] swz
    __shared__ int2  P[2][8][32];                    // 4KB per-tile partials
    __shared__ float csel_s[8][2][2][16];            // 4KB [w][h32][cv][r]

    const int t    = threadIdx.x;
    const int lane = t & 63;
    const int w    = t >> 6;          // wave 0..7
    const int l31  = lane & 31, h32 = lane >> 5;
    const int h    = blockIdx.y;
    const int half = blockIdx.z;
    const int rb0  = blockIdx.x * 1024;

    // ---- csel table: one value per thread ----
    {
        int ww = t >> 6, hb2 = (t >> 5) & 1, idx = t & 31;
        int cv = idx >> 4, r = idx & 15;
        int cr = (r & 3) + ((r >> 2) << 3);
        csel_s[ww][hb2][cv][r] =
            csq1024[h * kK + half * 512 + ww * 64 + hb2 * 4 + cv * 32 + cr];
    }

    // ---- per-lane key index addends: addv[cv][r] = cgb + cv*32 + cr ----
    const int cgb = half * 512 + w * 64 + h32 * 4;
    int addv[2][16];
    #pragma unroll
    for (int cv = 0; cv < 2; ++cv)
        #pragma unroll
        for (int r = 0; r < 16; ++r)
            addv[cv][r] = cgb + cv * 32 + (r & 3) + ((r >> 2) << 3);

    // ---- A panel: wave's 64 codes (kt = half*8 + w), hi/lo ----
    bf16x8 Ah[8][2], Al[8][2];
    {
        const char* base = (const char*)cbf
            + (((size_t)h * 16 + half * 8 + w) * 16) * 2048 + lane * 16;
        #pragma unroll
        for (int kc = 0; kc < 8; ++kc)
            #pragma unroll
            for (int cv = 0; cv < 2; ++cv) {
                const char* p = base + (size_t)(kc * 2 + cv) * 2048;
                Ah[kc][cv] = *(const bf16x8*)p;
                Al[kc][cv] = *(const bf16x8*)(p + 1024);
            }
    }

    float4 zA, zB;   // pending z loads (T14 issue-early / commit-late)
    auto issueZ = [&](int tile) {
        const float* zp = z + (size_t)(rb0 + tile * 32 + (t >> 4)) * (kNH * kD)
                            + h * kD + (t & 15) * 8;
        zA = *(const float4*)zp;
        zB = *(const float4*)(zp + 4);
    };
    // biased round-half-up bf16 split via v_perm (r7-proven numerics)
    auto commitZ = [&](int buf) {
        unsigned u0 = __float_as_uint(zA.x) + 0x8000u;
        unsigned u1 = __float_as_uint(zA.y) + 0x8000u;
        unsigned u2 = __float_as_uint(zA.z) + 0x8000u;
        unsigned u3 = __float_as_uint(zA.w) + 0x8000u;
        unsigned u4 = __float_as_uint(zB.x) + 0x8000u;
        unsigned u5 = __float_as_uint(zB.y) + 0x8000u;
        unsigned u6 = __float_as_uint(zB.z) + 0x8000u;
        unsigned u7 = __float_as_uint(zB.w) + 0x8000u;
        unsigned h01 = __builtin_amdgcn_perm(u1, u0, 0x07060302u);
        unsigned h23 = __builtin_amdgcn_perm(u3, u2, 0x07060302u);
        unsigned h45 = __builtin_amdgcn_perm(u5, u4, 0x07060302u);
        unsigned h67 = __builtin_amdgcn_perm(u7, u6, 0x07060302u);
        float r0 = zA.x - __uint_as_float(u0 & 0xffff0000u);
        float r1 = zA.y - __uint_as_float(u1 & 0xffff0000u);
        float r2 = zA.z - __uint_as_float(u2 & 0xffff0000u);
        float r3 = zA.w - __uint_as_float(u3 & 0xffff0000u);
        float r4 = zB.x - __uint_as_float(u4 & 0xffff0000u);
        float r5 = zB.y - __uint_as_float(u5 & 0xffff0000u);
        float r6 = zB.z - __uint_as_float(u6 & 0xffff0000u);
        float r7 = zB.w - __uint_as_float(u7 & 0xffff0000u);
        unsigned l01 = __builtin_amdgcn_perm(__float_as_uint(r1) + 0x8000u,
                                             __float_as_uint(r0) + 0x8000u, 0x07060302u);
        unsigned l23 = __builtin_amdgcn_perm(__float_as_uint(r3) + 0x8000u,
                                             __float_as_uint(r2) + 0x8000u, 0x07060302u);
        unsigned l45 = __builtin_amdgcn_perm(__float_as_uint(r5) + 0x8000u,
                                             __float_as_uint(r4) + 0x8000u, 0x07060302u);
        unsigned l67 = __builtin_amdgcn_perm(__float_as_uint(r7) + 0x8000u,
                                             __float_as_uint(r6) + 0x8000u, 0x07060302u);
        int rr = t >> 4, seg = t & 15;
        int off = rr * 256 + ((seg * 16) ^ ((rr & 15) << 4));
        uint4 hv = {h01, h23, h45, h67};
        uint4 lv = {l01, l23, l45, l67};
        *(uint4*)((char*)&zbuf[buf][0][0] + off) = hv;
        *(uint4*)((char*)&zbuf[buf][1][0] + off) = lv;
    };
    auto mergeP = [&](int pb, int tile) {   // threads 0..31 only
        int2 m = P[pb][0][t];
        int m1 = m.x, m2 = m.y;
        #pragma unroll
        for (int ww = 1; ww < 8; ++ww) {
            int2 p = P[pb][ww][t];
            int mx = max(m1, p.x);
            m1 = min(m1, p.x);
            m2 = min(min(m2, p.y), mx);
        }
        int gid = (rb0 + tile * 32 + t) * kNH + h;
        part[(size_t)gid * 2 + half] = make_int2(m1, m2);
    };

    issueZ(0);
    commitZ(0);
    __syncthreads();

    int cur = 0;
    for (int tile = 0; tile < 32; ++tile) {
        if (tile + 1 < 32) issueZ(tile + 1);
        if (tile > 0 && t < 32) mergeP(cur ^ 1, tile - 1);

        // ---- acc C-init = csq*1024 (LDS broadcast, 8 ds_read_b128) ----
        f32x16 acc0, acc1;
        __builtin_memcpy(&acc0, &csel_s[w][h32][0][0], 64);
        __builtin_memcpy(&acc1, &csel_s[w][h32][1][0], 64);

        const char* zh0 = (const char*)&zbuf[cur][0][0];
        const char* zl0 = (const char*)&zbuf[cur][1][0];
        const int boff = l31 * 256;
        const int swz  = (l31 & 15) << 4;
        __builtin_amdgcn_s_setprio(1);
        #pragma unroll
        for (int kc = 0; kc < 8; ++kc) {
            int col = (kc * 32 + h32 * 16) ^ swz;
            bf16x8 Bh = *(const bf16x8*)(zh0 + boff + col);
            bf16x8 Bl = *(const bf16x8*)(zl0 + boff + col);
            acc0 = __builtin_amdgcn_mfma_f32_32x32x16_bf16(Ah[kc][0], Bh, acc0, 0, 0, 0);
            acc1 = __builtin_amdgcn_mfma_f32_32x32x16_bf16(Ah[kc][1], Bh, acc1, 0, 0, 0);
            acc0 = __builtin_amdgcn_mfma_f32_32x32x16_bf16(Al[kc][0], Bh, acc0, 0, 0, 0);
            acc1 = __builtin_amdgcn_mfma_f32_32x32x16_bf16(Al[kc][1], Bh, acc1, 0, 0, 0);
            acc0 = __builtin_amdgcn_mfma_f32_32x32x16_bf16(Ah[kc][0], Bl, acc0, 0, 0, 0);
            acc1 = __builtin_amdgcn_mfma_f32_32x32x16_bf16(Ah[kc][1], Bl, acc1, 0, 0, 0);
        }
        __builtin_amdgcn_s_setprio(0);

        // ---- commitZ early: ds_writes drain under the key loop ----
        if (tile + 1 < 32) commitZ(cur ^ 1);

        // ---- per-lane top-2: acc IS the scaled score; 4 VALU per key ----
        int b1 = 0x7fffffff, b2 = 0x7fffffff;
        #pragma unroll
        for (int r = 0; r < 16; ++r) {
            {
                int key = (((int)acc0[r]) << 10) + addv[0][r];
                b2 = med3_i32(key, b1, b2);
                b1 = min(b1, key);
            }
            {
                int key = (((int)acc1[r]) << 10) + addv[1][r];
                b2 = med3_i32(key, b1, b2);
                b1 = min(b1, key);
            }
        }
        // fold the two half-wave code sets (same z-row in lane l and l+32)
        int o1 = __shfl_xor(b1, 32), o2 = __shfl_xor(b2, 32);
        int mx2 = max(b1, o1);
        int v1 = min(b1, o1);
        int v2 = min(min(b2, o2), mx2);
        if (h32 == 0) P[cur][w][l31] = make_int2(v1, v2);

        __syncthreads();
        cur ^= 1;
    }
    if (t < 32) mergeP(cur ^ 1, 31);
}

// ---------------------------------------------------------------------------
// Merge the two code-half partials per row: idx, worklist flag, zq gather.
// ---------------------------------------------------------------------------
__global__ __launch_bounds__(256)
void pq_merge(const int2* __restrict__ part, const float* __restrict__ cb,
              float* __restrict__ out_zq, float* __restrict__ out_idx,
              unsigned int* wl_count, unsigned int* wl, unsigned int wl_cap)
{
    __shared__ int idx_s[128];
    const int t = threadIdx.x;
    const int g0 = blockIdx.x * 128;
    if (t < 128) {
        int gid = g0 + t;
        int2 p0 = part[(size_t)gid * 2];
        int2 p1 = part[(size_t)gid * 2 + 1];
        int mx = max(p0.x, p1.x);
        int v1 = min(p0.x, p1.x);
        int v2 = min(min(p0.y, p1.y), mx);
        int idx = v1 & 1023;
        idx_s[t] = idx;
        out_idx[gid] = (float)idx;
        if (wl_cap > 0u && ((v2 >> 10) - (v1 >> 10)) <= kMarginQ) {
            unsigned int pos = atomicAdd(wl_count, 1u);
            if (pos < wl_cap) wl[pos] = (unsigned int)gid;
        }
    }
    __syncthreads();
    #pragma unroll
    for (int it = 0; it < 16; ++it) {
        int c = it * 256 + t;          // 0..4095 float4 chunks
        int row = c >> 5, c4 = c & 31;
        int gid = g0 + row;
        int b = gid >> 3, hh = gid & 7;
        *(float4*)(out_zq + (size_t)b * (kNH * kD) + hh * kD + c4 * 4) =
            *(const float4*)(cb + ((size_t)hh * kK + idx_s[row]) * kD + c4 * 4);
    }
}

// ---------------------------------------------------------------------------
// Mid-tier fallback (pre-scaled cbf: key uses acc + cs).
// ---------------------------------------------------------------------------
__global__ __launch_bounds__(256, 2)
void pq_coarse_mfma3(const float* __restrict__ z, const float* __restrict__ cb,
                     const unsigned short* __restrict__ cbf,
                     const float* __restrict__ csq1024,
                     float* __restrict__ out_zq, float* __restrict__ out_idx,
                     unsigned int* wl_count, unsigned int* wl, unsigned int wl_cap)
{
    __shared__ float csq_s[kK];
    __shared__ int   idx_s[BM];

    const int t    = threadIdx.x;
    const int h    = blockIdx.y;
    const int b0   = blockIdx.x * BM;
    const int lane = t & 63;
    const int w    = t >> 6;
    const int l31  = lane & 31, h32 = lane >> 5;

    *(float4*)&csq_s[t * 4] = *(const float4*)(csq1024 + h * kK + t * 4);

    bf16x8 Ah[8], Al[8];
    {
        const float* zr = z + (size_t)(b0 + w * 32 + l31) * (kNH * kD) + h * kD + h32 * 8;
        #pragma unroll
        for (int kc = 0; kc < 8; ++kc) {
            float4 a = *(const float4*)(zr + kc * 16);
            float4 b = *(const float4*)(zr + kc * 16 + 4);
            float f[8] = {a.x, a.y, a.z, a.w, b.x, b.y, b.z, b.w};
            bf16x8 hv, lv;
            #pragma unroll
            for (int j = 0; j < 8; ++j) {
                unsigned short hb = f2bf_rne(f[j]);
                hv[j] = (short)hb;
                lv[j] = (short)f2bf_rne(f[j] - bf2f(hb));
            }
            Ah[kc] = hv;
            Al[kc] = lv;
        }
    }
    __syncthreads();

    int b1[16], b2[16];
    #pragma unroll
    for (int r = 0; r < 16; ++r) { b1[r] = 0x7fffffff; b2[r] = 0x7fffffff; }

    const char* bbase = (const char*)cbf + (size_t)h * 524288 + lane * 16;
#define LDSLOT(kt_, kc_, s_)                                                  \
    {                                                                         \
        const char* p_ = bbase + (size_t)(((kt_) * 8 + (kc_)) * 2) * 2048;    \
        Bh0[s_] = *(const bf16x8*)(p_);                                       \
        Bl0[s_] = *(const bf16x8*)(p_ + 1024);                                \
        Bh1[s_] = *(const bf16x8*)(p_ + 2048);                                \
        Bl1[s_] = *(const bf16x8*)(p_ + 3072);                                \
    }

    bf16x8 Bh0[4], Bl0[4], Bh1[4], Bl1[4];
    LDSLOT(0, 0, 0);
    LDSLOT(0, 1, 1);

    for (int kt = 0; kt < 16; ++kt) {
        f32x16 acc0 = (f32x16)0.0f, acc1 = (f32x16)0.0f;
        const int ktn = (kt + 1 < 16) ? kt + 1 : kt;
        #pragma unroll
        for (int kc = 0; kc < 8; ++kc) {
            const int s  = kc & 3;
            const int s2 = (kc + 2) & 3;
            if (kc < 6) { LDSLOT(kt, kc + 2, s2); } else { LDSLOT(ktn, kc - 6, s2); }
            __builtin_amdgcn_s_setprio(1);
            acc0 = __builtin_amdgcn_mfma_f32_32x32x16_bf16(Ah[kc], Bh0[s], acc0, 0, 0, 0);
            acc1 = __builtin_amdgcn_mfma_f32_32x32x16_bf16(Ah[kc], Bh1[s], acc1, 0, 0, 0);
            acc0 = __builtin_amdgcn_mfma_f32_32x32x16_bf16(Al[kc], Bh0[s], acc0, 0, 0, 0);
            acc1 = __builtin_amdgcn_mfma_f32_32x32x16_bf16(Al[kc], Bh1[s], acc1, 0, 0, 0);
            acc0 = __builtin_amdgcn_mfma_f32_32x32x16_bf16(Ah[kc], Bl0[s], acc0, 0, 0, 0);
            acc1 = __builtin_amdgcn_mfma_f32_32x32x16_bf16(Ah[kc], Bl1[s], acc1, 0, 0, 0);
            __builtin_amdgcn_s_setprio(0);
        }
        const float cs0 = csq_s[kt * 64 + l31];
        const float cs1 = csq_s[kt * 64 + 32 + l31];
        const int   kg0 = kt * 64 + l31, kg1 = kg0 + 32;
        #pragma unroll
        for (int r = 0; r < 16; ++r) {
            {
                float kf = acc0[r] + cs0;   // cbf pre-scaled by -2048
                int key = ((int)kf << 10) + kg0;
                int mx = max(b1[r], key); b1[r] = min(b1[r], key); b2[r] = min(b2[r], mx);
            }
            {
                float kf = acc1[r] + cs1;
                int key = ((int)kf << 10) + kg1;
                int mx = max(b1[r], key); b1[r] = min(b1[r], key); b2[r] = min(b2[r], mx);
            }
        }
    }
#undef LDSLOT

    #pragma unroll
    for (int r = 0; r < 16; ++r) {
        int v1 = b1[r], v2 = b2[r];
        #pragma unroll
        for (int m = 1; m < 32; m <<= 1) {
            int o1 = __shfl_xor(v1, m);
            int o2 = __shfl_xor(v2, m);
            int mx = max(v1, o1);
            v1 = min(v1, o1);
            v2 = min(min(v2, o2), mx);
        }
        if (l31 == 0) {
            int row = w * 32 + (r & 3) + ((r >> 2) << 3) + h32 * 4;
            int idx = v1 & 1023;
            idx_s[row] = idx;
            int gid = (b0 + row) * kNH + h;
            out_idx[gid] = (float)idx;
            if (wl_cap > 0u && ((v2 >> 10) - (v1 >> 10)) <= kMarginQ) {
                unsigned int pos = atomicAdd(wl_count, 1u);
                if (pos < wl_cap) wl[pos] = (unsigned int)gid;
            }
        }
    }
    __syncthreads();
    {
        const float* cbh_row = cb + (size_t)h * kK * kD;
        #pragma unroll
        for (int it = 0; it < 16; ++it) {
            int c = it * 256 + t;
            int row = c >> 5, col4 = c & 31;
            *(float4*)(out_zq + (size_t)(b0 + row) * (kNH * kD) + h * kD + col4 * 4) =
                *(const float4*)(cbh_row + (size_t)idx_s[row] * kD + col4 * 4);
        }
    }
}

// ---------------------------------------------------------------------------
// Fallback fp32 coarse pass (round-1, proven) — used only if ws tiny.
// ---------------------------------------------------------------------------
__global__ __launch_bounds__(256, 2)
void pq_coarse_f32(const float* __restrict__ z, const float* __restrict__ cb,
                   float* __restrict__ out_zq, float* __restrict__ out_idx,
                   unsigned int* wl_count, unsigned int* wl, unsigned int wl_cap)
{
    constexpr int KT = 64, PAD = 68, BMF = 64;
    __shared__ float zT[kD][PAD];
    __shared__ float cT[kD][PAD];
    __shared__ float csq_s[KT];
    __shared__ int   bidx_s[BMF];

    const int t  = threadIdx.x;
    const int h  = blockIdx.y;
    const int b0 = blockIdx.x * BMF;
    const int tx = t & 15, ty = t >> 4;
    const int r8 = t & 7,  d4 = t >> 3;

    {
        const float* zp = z + (size_t)(b0 + r8) * (kNH * kD) + h * kD + 4 * d4;
        #pragma unroll
        for (int it = 0; it < BMF / 8; ++it) {
            float4 v = *(const float4*)(zp + (size_t)(8 * it) * (kNH * kD));
            int r = r8 + 8 * it;
            zT[4 * d4 + 0][r] = v.x; zT[4 * d4 + 1][r] = v.y;
            zT[4 * d4 + 2][r] = v.z; zT[4 * d4 + 3][r] = v.w;
        }
    }
    float best1[4], best2[4]; int ibest[4];
    #pragma unroll
    for (int i = 0; i < 4; ++i) { best1[i] = 3.4e38f; best2[i] = 3.4e38f; ibest[i] = 0; }

    for (int kt = 0; kt < kK / KT; ++kt) {
        __syncthreads();
        {
            const float* cp = cb + ((size_t)h * kK + kt * KT + r8) * kD + 4 * d4;
            #pragma unroll
            for (int it = 0; it < KT / 8; ++it) {
                float4 v = *(const float4*)(cp + (size_t)(8 * it) * kD);
                int r = r8 + 8 * it;
                cT[4 * d4 + 0][r] = v.x; cT[4 * d4 + 1][r] = v.y;
                cT[4 * d4 + 2][r] = v.z; cT[4 * d4 + 3][r] = v.w;
            }
        }
        if (t < KT) csq_s[t] = 0.0f;
        __syncthreads();
        {
            int kk = t & 63, part = t >> 6;
            float s = 0.f;
            #pragma unroll
            for (int i = 0; i < 32; ++i) { float v = cT[32 * part + i][kk]; s = fmaf(v, v, s); }
            atomicAdd(&csq_s[kk], s);
        }
        __syncthreads();
        float accA[4][4] = {{0}}, accB[4][4] = {{0}};
        #pragma unroll 2
        for (int d = 0; d < kD; d += 2) {
            float4 za = *(const float4*)&zT[d][4 * ty];
            float4 ca = *(const float4*)&cT[d][4 * tx];
            float4 zb = *(const float4*)&zT[d + 1][4 * ty];
            float4 cv = *(const float4*)&cT[d + 1][4 * tx];
            float zav[4] = {za.x, za.y, za.z, za.w}, cav[4] = {ca.x, ca.y, ca.z, ca.w};
            float zbv[4] = {zb.x, zb.y, zb.z, zb.w}, cbv[4] = {cv.x, cv.y, cv.z, cv.w};
            #pragma unroll
            for (int i = 0; i < 4; ++i)
                #pragma unroll
                for (int j = 0; j < 4; ++j) {
                    accA[i][j] = fmaf(zav[i], cav[j], accA[i][j]);
                    accB[i][j] = fmaf(zbv[i], cbv[j], accB[i][j]);
                }
        }
        #pragma unroll
        for (int j = 0; j < 4; ++j) {
            int kk = 4 * tx + j;
            float cs = csq_s[kk];
            int kg = kt * KT + kk;
            #pragma unroll
            for (int i = 0; i < 4; ++i) {
                float s = fmaf(-2.0f, accA[i][j] + accB[i][j], cs);
                if (s < best1[i]) { best2[i] = best1[i]; best1[i] = s; ibest[i] = kg; }
                else if (s < best2[i]) { best2[i] = s; }
            }
        }
    }
    __syncthreads();
    float* redv1 = &zT[0][0];
    float* redv2 = redv1 + BMF * 16;
    int*   redi  = (int*)(redv2 + BMF * 16);
    #pragma unroll
    for (int i = 0; i < 4; ++i) {
        int r = 4 * ty + i;
        redv1[r * 16 + tx] = best1[i]; redv2[r * 16 + tx] = best2[i]; redi[r * 16 + tx] = ibest[i];
    }
    __syncthreads();
    if (t < BMF) {
        int r = t;
        float vb1_ = redv1[r * 16], vb2_ = redv2[r * 16];
        int i1 = redi[r * 16];
        #pragma unroll
        for (int x = 1; x < 16; ++x) {
            float nb1 = redv1[r * 16 + x], nb2 = redv2[r * 16 + x];
            int ni1 = redi[r * 16 + x];
            if (nb1 < vb1_ || (nb1 == vb1_ && ni1 < i1)) { vb2_ = fminf(vb1_, nb2); vb1_ = nb1; i1 = ni1; }
            else vb2_ = fminf(vb2_, nb1);
        }
        bidx_s[r] = i1;
        int gid = (b0 + r) * kNH + h;
        out_idx[gid] = (float)i1;
        if (wl_cap > 0u && (vb2_ - vb1_) <= kMarginF32) {
            unsigned int pos = atomicAdd(wl_count, 1u);
            if (pos < wl_cap) wl[pos] = (unsigned int)gid;
        }
    }
    __syncthreads();
    {
        int r = t >> 2, q = t & 3;
        const float* src = cb + ((size_t)h * kK + bidx_s[r]) * kD;
        float* dst = out_zq + (size_t)(b0 + r) * (kNH * kD) + h * kD;
        #pragma unroll
        for (int m = 0; m < 8; ++m) {
            int jj = 4 * m + q;
            *(float4*)(dst + 4 * jj) = *(const float4*)(src + 4 * jj);
        }
    }
}

// ---------------------------------------------------------------------------
// Exact fp64 rescore for flagged pairs.
// ---------------------------------------------------------------------------
__global__ __launch_bounds__(256)
void pq_exact(const float* __restrict__ z, const float* __restrict__ cb,
              float* __restrict__ out_zq, float* __restrict__ out_idx,
              const unsigned int* wl_count, const unsigned int* wl,
              unsigned int wl_cap)
{
    if (wl_cap == 0u) return;
    __shared__ float  zs[kD];
    __shared__ double rv[256];
    __shared__ int    ri[256];
    unsigned int n = *wl_count;
    if (n > wl_cap) n = wl_cap;
    const int t = threadIdx.x;
    for (unsigned int e = blockIdx.x; e < n; e += gridDim.x) {
        unsigned int id = wl[e];
        int b = (int)(id / kNH), h = (int)(id % kNH);
        if (t < kD) zs[t] = z[(size_t)b * (kNH * kD) + h * kD + t];
        __syncthreads();
        double bv = 1e300; int bi = 0;
        #pragma unroll
        for (int kk = 0; kk < 4; ++kk) {
            int k = t * 4 + kk;
            const float* c = cb + ((size_t)h * kK + k) * kD;
            double s = 0.0;
            for (int d = 0; d < kD; ++d) {
                double diff = (double)zs[d] - (double)c[d];
                s = fma(diff, diff, s);
            }
            if (s < bv) { bv = s; bi = k; }
        }
        rv[t] = bv; ri[t] = bi;
        __syncthreads();
        for (int s2 = 128; s2 > 0; s2 >>= 1) {
            if (t < s2) {
                if (rv[t + s2] < rv[t] || (rv[t + s2] == rv[t] && ri[t + s2] < ri[t])) {
                    rv[t] = rv[t + s2]; ri[t] = ri[t + s2];
                }
            }
            __syncthreads();
        }
        int kbest = ri[0];
        if (t == 0) out_idx[id] = (float)kbest;
        if (t < kD)
            out_zq[(size_t)b * (kNH * kD) + h * kD + t] =
                cb[((size_t)h * kK + kbest) * kD + t];
        __syncthreads();
    }
}

extern "C" void kernel_launch(void* const* d_in, const int* in_sizes, int n_in,
                              void* d_out, int out_size, void* d_ws, size_t ws_size,
                              hipStream_t stream)
{
    const float* z  = (const float*)d_in[0];
    const float* cb = (const float*)d_in[1];
    float* out_zq  = (float*)d_out;
    float* out_idx = out_zq + (size_t)kB * kNH * kD;
    char* ws = (char*)d_ws;

    if (ws_size >= kOffWl6 + 65536) {
        // ---- top tier: code-owning waves, VALU-lean inner loop ----
        unsigned int* wl_count = (unsigned int*)ws;
        unsigned int* wl = (unsigned int*)(ws + kOffWl6);
        size_t c = (ws_size - kOffWl6) / 4;
        unsigned int cap = (unsigned int)(c > 262144 ? 262144 : c);
        float* csq = (float*)(ws + kOffCsq);
        unsigned short* cbf = (unsigned short*)(ws + kOffCbF);
        int2* part = (int2*)(ws + kOffPart);

        hipMemsetAsync(d_ws, 0, 4, stream);
        pq_prep<<<kNH * kK, kD, 0, stream>>>(cb, cbf, csq);
        dim3 grid(32, kNH, 2);
        pq_coarse_mfma7<<<grid, 512, 0, stream>>>(z, cbf, csq, part);
        pq_merge<<<kB * kNH / 128, 256, 0, stream>>>(part, cb, out_zq, out_idx,
                                                     wl_count, wl, cap);
        pq_exact<<<256, 256, 0, stream>>>(z, cb, out_zq, out_idx, wl_count, wl, cap);
    } else if (ws_size >= kOffWl5 + 4096) {
        // ---- mid-tier ----
        unsigned int* wl_count = (unsigned int*)ws;
        unsigned int* wl = (unsigned int*)(ws + kOffWl5);
        size_t c = (ws_size - kOffWl5) / 4;
        unsigned int cap = (unsigned int)(c > 262144 ? 262144 : c);
        float* csq = (float*)(ws + kOffCsq);
        unsigned short* cbf = (unsigned short*)(ws + kOffCbF);

        hipMemsetAsync(d_ws, 0, 4, stream);
        pq_prep<<<kNH * kK, kD, 0, stream>>>(cb, cbf, csq);
        dim3 grid(kB / BM, kNH);
        pq_coarse_mfma3<<<grid, 256, 0, stream>>>(z, cb, cbf, csq,
                                                  out_zq, out_idx, wl_count, wl, cap);
        pq_exact<<<256, 256, 0, stream>>>(z, cb, out_zq, out_idx, wl_count, wl, cap);
    } else {
        unsigned int* wl_count = (unsigned int*)ws;
        unsigned int* wl = wl_count + 1;
        unsigned int cap = 0;
        if (ws_size >= 64) {
            size_t c = ws_size / 4 - 1;
            cap = (unsigned int)(c > 262144 ? 262144 : c);
            hipMemsetAsync(d_ws, 0, 4, stream);
        }
        dim3 grid(kB / 64, kNH);
        pq_coarse_f32<<<grid, 256, 0, stream>>>(z, cb, out_zq, out_idx, wl_count, wl, cap);
        pq_exact<<<256, 256, 0, stream>>>(z, cb, out_zq, out_idx, wl_count, wl, cap);
    }
}